// Round 1
// baseline (39.870 us; speedup 1.0000x reference)
//
#include <hip/hip_runtime.h>

typedef __attribute__((ext_vector_type(8))) short bf16x8;
typedef __attribute__((ext_vector_type(4))) float f32x4;

// round-to-nearest-even fp32 -> bf16 (bit pattern in a short)
__device__ __forceinline__ short f2bs(float f) {
    unsigned int u = __float_as_uint(f);
    unsigned int r = (u + 0x7fffu + ((u >> 16) & 1u)) >> 16;
    return (short)r;
}

// ---------------------------------------------------------------------------
// prep kernel: pack Wc = [W1 | ref^T] (256 x 96) and W2 (32 x 16) into bf16
// MFMA B-fragment order, compute r2[j] = ||ref_j||^2.
//   wcfrag layout: [kt(8)][nt(6)][lane(64)][j(8)]  (ushort)
//     k = kt*32 + (lane>>4)*8 + j ; col = nt*16 + (lane&15)
//   w2frag layout: [lane(64)][j(8)]  k=(lane>>4)*8+j, col=lane&15
// ---------------------------------------------------------------------------
__global__ void prep_kernel(const float* __restrict__ W1,
                            const float* __restrict__ ref,
                            const float* __restrict__ W2,
                            float* __restrict__ r2,
                            unsigned short* __restrict__ wcfrag,
                            unsigned short* __restrict__ w2frag) {
    int idx = blockIdx.x * 256 + threadIdx.x;
    if (idx < 24576) {
        int j    = idx & 7;
        int lane = (idx >> 3) & 63;
        int nt   = (idx >> 9) % 6;
        int kt   = idx / 3072;
        int k    = kt * 32 + (lane >> 4) * 8 + j;
        int col  = nt * 16 + (lane & 15);
        float w  = (col < 32) ? W1[k * 32 + col] : ref[(col - 32) * 256 + k];
        wcfrag[idx] = (unsigned short)f2bs(w);
    } else if (idx < 24576 + 512) {
        int t    = idx - 24576;
        int j    = t & 7;
        int lane = t >> 3;
        int k    = (lane >> 4) * 8 + j;
        int col  = lane & 15;
        w2frag[t] = (unsigned short)f2bs(W2[k * 16 + col]);
    } else if (idx < 24576 + 512 + 64) {
        int t = idx - (24576 + 512);
        float s = 0.f;
        for (int k = 0; k < 256; ++k) {
            float v = ref[t * 256 + k];
            s += v * v;
        }
        r2[t] = s;
    }
}

// ---------------------------------------------------------------------------
// main fused kernel: 256 threads (4 waves), 128 rows per block.
// Y = x @ [W1|ref^T] via mfma 16x16x32 bf16; fused epilogue:
//   h1 = relu(Y[:, :32]+b1) ; h2 = relu(h1@W2+b2) (2nd MFMA)
//   kf = exp(-(x2 + r2 - 2*Y[:,32:])) ; out = h2@Wf[:16] + kf@Wf[16:] + bf
// No barriers in the K loop (weights are read-only LDS; waves own disjoint rows).
// ---------------------------------------------------------------------------
__global__ __launch_bounds__(256) void fused_kernel(
        const float* __restrict__ x,
        const float* __restrict__ b1,
        const float* __restrict__ b2,
        const float* __restrict__ Wf,
        const float* __restrict__ bfp,
        const float* __restrict__ r2g,
        const unsigned short* __restrict__ wcfrag,
        const unsigned short* __restrict__ w2frag,
        float* __restrict__ out) {
    __shared__ unsigned short wc[8][6][64][8];   // 48 KB, fragment order
    __shared__ unsigned short h1lds[128][40];    // 10 KB (80B row stride, 16B-aligned reads)
    __shared__ float r2s[64];
    __shared__ float b1s[32];
    __shared__ float b2s[16];
    __shared__ float Wfs[80];
    __shared__ float x2s[128];
    __shared__ float bfs;

    const int tid  = threadIdx.x;
    const int lane = tid & 63;
    const int w    = tid >> 6;

    // ---- prologue: stage weights ----
    {
        const int4* src = (const int4*)wcfrag;   // 24576 ushort = 3072 int4
        int4* dst = (int4*)&wc[0][0][0][0];
        #pragma unroll
        for (int i = 0; i < 12; ++i) dst[tid + i * 256] = src[tid + i * 256];
    }
    if (tid < 64) r2s[tid] = r2g[tid];
    if (tid < 32) b1s[tid] = b1[tid];
    if (tid < 16) b2s[tid] = b2[tid];
    if (tid < 80) Wfs[tid] = Wf[tid];
    if (tid == 0) bfs = bfp[0];
    __syncthreads();

    // ---- K loop: Y = x @ Wc ----
    const int rowblk = w * 32;                        // wave's row base within block
    const long long r0 = (long long)blockIdx.x * 128 + rowblk + (lane & 15);
    const float* xp0 = x + r0 * 256 + ((lane >> 4) * 8);
    const float* xp1 = xp0 + 16 * 256;

    f32x4 acc[2][6];
    #pragma unroll
    for (int fr = 0; fr < 2; ++fr)
        #pragma unroll
        for (int nt = 0; nt < 6; ++nt)
            acc[fr][nt] = (f32x4){0.f, 0.f, 0.f, 0.f};

    float x2p0 = 0.f, x2p1 = 0.f;

    #pragma unroll 2
    for (int kt = 0; kt < 8; ++kt) {
        const f32x4* p0 = (const f32x4*)(xp0 + kt * 32);
        const f32x4* p1 = (const f32x4*)(xp1 + kt * 32);
        f32x4 u0 = p0[0], u1 = p0[1];
        f32x4 v0 = p1[0], v1 = p1[1];

        bf16x8 a0, a1;
        #pragma unroll
        for (int j = 0; j < 4; ++j) {
            a0[j]     = f2bs(u0[j]);
            a0[j + 4] = f2bs(u1[j]);
            a1[j]     = f2bs(v0[j]);
            a1[j + 4] = f2bs(v1[j]);
            x2p0 += u0[j] * u0[j] + u1[j] * u1[j];
            x2p1 += v0[j] * v0[j] + v1[j] * v1[j];
        }

        #pragma unroll
        for (int nt = 0; nt < 6; ++nt) {
            bf16x8 bfr = *(const bf16x8*)&wc[kt][nt][lane][0];
            acc[0][nt] = __builtin_amdgcn_mfma_f32_16x16x32_bf16(a0, bfr, acc[0][nt], 0, 0, 0);
            acc[1][nt] = __builtin_amdgcn_mfma_f32_16x16x32_bf16(a1, bfr, acc[1][nt], 0, 0, 0);
        }
    }

    // ---- x2: reduce over the 4 k-groups (lanes xor 16, 32) ----
    x2p0 += __shfl_xor(x2p0, 16);
    x2p0 += __shfl_xor(x2p0, 32);
    x2p1 += __shfl_xor(x2p1, 16);
    x2p1 += __shfl_xor(x2p1, 32);
    if (lane < 16) {
        x2s[rowblk + lane]      = x2p0;
        x2s[rowblk + 16 + lane] = x2p1;
    }

    // ---- h1 = relu(Y[:, :32] + b1) -> LDS (bf16, transposed for 2nd MFMA) ----
    #pragma unroll
    for (int fr = 0; fr < 2; ++fr)
        #pragma unroll
        for (int nt = 0; nt < 2; ++nt)
            #pragma unroll
            for (int r = 0; r < 4; ++r) {
                int row = rowblk + fr * 16 + (lane >> 4) * 4 + r;
                int col = nt * 16 + (lane & 15);
                float hv = fmaxf(acc[fr][nt][r] + b1s[col], 0.f);
                h1lds[row][col] = (unsigned short)f2bs(hv);
            }
    // same-wave LDS RAW only (each wave owns its 32 rows): no barrier needed.

    // ---- h2 = relu(h1 @ W2 + b2) via MFMA ----
    bf16x8 w2f = *(const bf16x8*)(w2frag + lane * 8);
    f32x4 hacc[2];
    #pragma unroll
    for (int fr = 0; fr < 2; ++fr) {
        int row = rowblk + fr * 16 + (lane & 15);
        bf16x8 af = *(const bf16x8*)&h1lds[row][(lane >> 4) * 8];
        f32x4 z = (f32x4){0.f, 0.f, 0.f, 0.f};
        hacc[fr] = __builtin_amdgcn_mfma_f32_16x16x32_bf16(af, w2f, z, 0, 0, 0);
    }

    // ---- combine: out = h2@Wf[:16] + kf@Wf[16:] + bf ----
    const int colm = lane & 15;
    const float wfm = Wfs[colm];
    #pragma unroll
    for (int fr = 0; fr < 2; ++fr) {
        float osum[4];
        #pragma unroll
        for (int r = 0; r < 4; ++r) {
            int row = rowblk + fr * 16 + (lane >> 4) * 4 + r;
            float h2v = fmaxf(hacc[fr][r] + b2s[colm], 0.f);
            float s = h2v * wfm;
            float x2v = x2s[row];
            #pragma unroll
            for (int nt = 2; nt < 6; ++nt) {
                int jj = (nt - 2) * 16 + colm;
                float sq = x2v + r2s[jj] - 2.f * acc[fr][nt][r];
                s += __expf(-sq) * Wfs[16 + jj];
            }
            // butterfly sum over the 16 lanes sharing this row
            s += __shfl_xor(s, 1);
            s += __shfl_xor(s, 2);
            s += __shfl_xor(s, 4);
            s += __shfl_xor(s, 8);
            osum[r] = s + bfs;
        }
        if (colm == 0) {
            long long rowg = (long long)blockIdx.x * 128 + rowblk + fr * 16 + (lane >> 4) * 4;
            #pragma unroll
            for (int r = 0; r < 4; ++r) out[rowg + r] = osum[r];
        }
    }
}

extern "C" void kernel_launch(void* const* d_in, const int* in_sizes, int n_in,
                              void* d_out, int out_size, void* d_ws, size_t ws_size,
                              hipStream_t stream) {
    const float* x   = (const float*)d_in[0];
    const float* W1  = (const float*)d_in[1];
    const float* b1  = (const float*)d_in[2];
    const float* W2  = (const float*)d_in[3];
    const float* b2  = (const float*)d_in[4];
    const float* ref = (const float*)d_in[5];
    const float* Wf  = (const float*)d_in[6];
    const float* bf_ = (const float*)d_in[7];
    float* out = (float*)d_out;

    const int B = in_sizes[0] / 256;

    unsigned short* wcfrag = (unsigned short*)d_ws;                      // 49152 B
    unsigned short* w2frag = (unsigned short*)((char*)d_ws + 49152);     // 1024 B
    float*          r2     = (float*)((char*)d_ws + 49152 + 1024);       // 256 B

    hipLaunchKernelGGL(prep_kernel, dim3(99), dim3(256), 0, stream,
                       W1, ref, W2, r2, wcfrag, w2frag);
    hipLaunchKernelGGL(fused_kernel, dim3(B / 128), dim3(256), 0, stream,
                       x, b1, b2, Wf, bf_, r2, wcfrag, w2frag, out);
}